// Round 11
// baseline (152.134 us; speedup 1.0000x reference)
//
#include <hip/hip_runtime.h>
#include <hip/hip_bf16.h>
#include <stdint.h>

#define SEQ   2048
#define DIM   512
#define BATCH 4

typedef __attribute__((ext_vector_type(8)))  short  short8;
typedef __attribute__((ext_vector_type(4)))  float  floatx4;
typedef __attribute__((ext_vector_type(16))) float  floatx16;

static __device__ __forceinline__ unsigned short f2b(float f) {
  return __builtin_bit_cast(unsigned short, __float2bfloat16(f));
}

// async 16B/lane global->LDS (global_load_lds_dwordx4)
static __device__ __forceinline__ void gll16(const void* g, void* l) {
  __builtin_amdgcn_global_load_lds(
      (__attribute__((address_space(1))) void*)(uintptr_t)g,
      (__attribute__((address_space(3))) void*)l, 16, 0, 0);
}

// ---------------------------------------------------------------------------
// F-layout (16-row frags, verified R4/R9): 1KB = 16 rows x 32 k;
//   frag = (row>>4)*TK + (k>>5); lane = ((k>>3)&3)*16 + (row&15); elem = k&7.
// G-layout (32-row frags, for mfma_f32_32x32x16_bf16): 1KB = 32 rows x 16 k;
//   frag = (row>>5)*TK + (k>>4); lane = ((k>>3)&1)*32 + (row&31); elem = k&7.
// 32x32 C/D: col = lane&31, row = (reg&3) + 8*(reg>>2) + 4*(lane>>5).
// ---------------------------------------------------------------------------

// --- 16x16 path (qkv mainloop, R9-verified) --------------------------------
template <int BF>
__device__ __forceinline__ void fgemm_lds(
    const char* __restrict__ A, int rtA0, int TKA,
    const char* __restrict__ B, int rtB0, int TKB,
    int kIters, char* lds, floatx4 (&acc)[4][BF / 2])
{
  constexpr int BUF = (8 + BF) * 1024;
  const int tid = threadIdx.x;
  const int w = tid >> 6, l = tid & 63;
  const int wmf = (w & 1) * 4;
  const int wnf = (w >> 1) * (BF / 2);

  auto stage = [&](int p, int kt) {
    char* dst = lds + p * BUF;
#pragma unroll
    for (int q = 0; q < 2; ++q) {
      const int f = q * 4 + w;
      gll16(A + (((size_t)(rtA0 + f) * TKA + kt) << 10) + l * 16,
            dst + f * 1024 + l * 16);
    }
#pragma unroll
    for (int q = 0; q < BF / 4; ++q) {
      const int f = q * 4 + w;
      gll16(B + (((size_t)(rtB0 + f) * TKB + kt) << 10) + l * 16,
            dst + 8192 + f * 1024 + l * 16);
    }
  };

  stage(0, 0);
  __syncthreads();

  for (int kt = 0; kt < kIters; ++kt) {
    const int p = kt & 1;
    if (kt + 1 < kIters) stage(1 - p, kt + 1);

    const char* bA = lds + p * BUF;
    const char* bB = bA + 8192;
    short8 af[4], bf[BF / 2];
#pragma unroll
    for (int i = 0; i < 4; ++i)
      af[i] = *(const short8*)(bA + (wmf + i) * 1024 + l * 16);
#pragma unroll
    for (int j = 0; j < BF / 2; ++j)
      bf[j] = *(const short8*)(bB + (wnf + j) * 1024 + l * 16);

#pragma unroll
    for (int i = 0; i < 4; ++i)
#pragma unroll
      for (int j = 0; j < BF / 2; ++j)
        acc[i][j] = __builtin_amdgcn_mfma_f32_16x16x32_bf16(af[i], bf[j], acc[i][j], 0, 0, 0);

    __syncthreads();
  }
}

// --- 32x32 path: 128x128 tile, 4 waves (2x2 of 64x64), KC frag-cols/step ---
template <int KC>
__device__ __forceinline__ void fgemm32(
    const char* __restrict__ A, int rtA0, int TKA,
    const char* __restrict__ B, int rtB0, int TKB,
    int kIters, char* lds, floatx16 (&acc)[2][2])
{
  constexpr int BUF = 8 * KC * 1024;
  const int tid = threadIdx.x;
  const int w = tid >> 6, l = tid & 63;
  const int wm = w & 1, wn = w >> 1;

  auto stage = [&](int p, int kt) {
    char* dst = lds + p * BUF;
#pragma unroll
    for (int c = 0; c < KC; ++c) {
      gll16(A + (((size_t)(rtA0 + w) * TKA + kt * KC + c) << 10) + l * 16,
            dst + (c * 8 + w) * 1024 + l * 16);
      gll16(B + (((size_t)(rtB0 + w) * TKB + kt * KC + c) << 10) + l * 16,
            dst + (c * 8 + 4 + w) * 1024 + l * 16);
    }
  };

  stage(0, 0);
  __syncthreads();

  for (int kt = 0; kt < kIters; ++kt) {
    const int p = kt & 1;
    if (kt + 1 < kIters) stage(1 - p, kt + 1);

    const char* buf = lds + p * BUF;
    short8 af[KC][2], bf[KC][2];
#pragma unroll
    for (int c = 0; c < KC; ++c) {
#pragma unroll
      for (int i = 0; i < 2; ++i)
        af[c][i] = *(const short8*)(buf + (c * 8 + wm * 2 + i) * 1024 + l * 16);
#pragma unroll
      for (int j = 0; j < 2; ++j)
        bf[c][j] = *(const short8*)(buf + (c * 8 + 4 + wn * 2 + j) * 1024 + l * 16);
    }
#pragma unroll
    for (int c = 0; c < KC; ++c)
#pragma unroll
      for (int i = 0; i < 2; ++i)
#pragma unroll
        for (int j = 0; j < 2; ++j)
          acc[i][j] = __builtin_amdgcn_mfma_f32_32x32x16_bf16(af[c][i], bf[c][j], acc[i][j], 0, 0, 0);

    __syncthreads();
  }
}

// ---- K0: setup: X->XbF, W->WF (F-layout, unchanged), zero rowsum ----------
__global__ __launch_bounds__(256) void setup_kernel(
    const float* __restrict__ X, const float* __restrict__ Wq,
    const float* __restrict__ Wk, const float* __restrict__ Wv,
    short8* __restrict__ XbF, short8* __restrict__ WF,
    float* __restrict__ rowsum)
{
  const int flat = blockIdx.x * 256 + threadIdx.x;   // 0..524287
  {
    const int tile = flat >> 6, l = flat & 63;
    const int row = (tile >> 4) * 16 + (l & 15);
    const int k0  = (tile & 15) * 32 + (l >> 4) * 8;
    const float4 v0 = *(const float4*)(X + (size_t)row * DIM + k0);
    const float4 v1 = *(const float4*)(X + (size_t)row * DIM + k0 + 4);
    short8 o;
    o[0] = (short)f2b(v0.x); o[1] = (short)f2b(v0.y);
    o[2] = (short)f2b(v0.z); o[3] = (short)f2b(v0.w);
    o[4] = (short)f2b(v1.x); o[5] = (short)f2b(v1.y);
    o[6] = (short)f2b(v1.z); o[7] = (short)f2b(v1.w);
    XbF[flat] = o;
  }
  if (flat < 3 * 32768) {
    const int z = flat >> 15, within = flat & 32767;
    const float* W = (z == 0) ? Wq : (z == 1) ? Wk : Wv;
    const int tile = within >> 6, l = within & 63;
    const int n  = (tile >> 4) * 16 + (l & 15);
    const int k0 = (tile & 15) * 32 + (l >> 4) * 8;
    short8 o;
#pragma unroll
    for (int e = 0; e < 8; ++e)
      o[e] = (short)f2b(W[(size_t)(k0 + e) * DIM + n]);
    WF[flat] = o;
  }
  if (flat < 2048) ((float4*)rowsum)[flat] = float4{0.f, 0.f, 0.f, 0.f};
}

// ---- K1: QKV (16x16 mainloop, R9); epilogues store G-layout ---------------
__global__ __launch_bounds__(256) void qkv_kernel(
    const short8* __restrict__ XbF, const short8* __restrict__ WF,
    const float* __restrict__ bq, const float* __restrict__ bk,
    const float* __restrict__ bv,
    unsigned short* __restrict__ QF, unsigned short* __restrict__ KF,
    unsigned short* __restrict__ VF)
{
  __shared__ char lds[32768];
  const int z = blockIdx.z, x = blockIdx.x, y = blockIdx.y;
  const int lane = threadIdx.x & 63, w = threadIdx.x >> 6;
  const char* Xc = (const char*)XbF;
  const char* Wc = (const char*)WF;
  floatx4 acc[4][4] = {};

  if (z < 2) {
    // C rows=d, cols=s. QF/KF: G-layout rows=s (32-frags, TK=32), K=d.
    fgemm_lds<8>(Wc + (size_t)z * 524288, y * 8, 16, Xc, x * 8, 16, 16, lds, acc);
    const float* bias = z ? bk : bq;
    unsigned short* OF = z ? KF : QF;
    const int dbase = y * 128 + (w & 1) * 64;
    const int sbase = x * 128 + (w >> 1) * 64;
#pragma unroll
    for (int i = 0; i < 4; ++i) {
      const int d0 = dbase + i * 16 + (lane >> 4) * 4;
      const float4 b4 = *(const float4*)(bias + d0);
#pragma unroll
      for (int j = 0; j < 4; ++j) {
        const int s = sbase + j * 16 + (lane & 15);
        ushort4 pk;
        pk.x = f2b(acc[i][j][0] + b4.x);
        pk.y = f2b(acc[i][j][1] + b4.y);
        pk.z = f2b(acc[i][j][2] + b4.z);
        pk.w = f2b(acc[i][j][3] + b4.w);
        *(ushort4*)(OF + (size_t)((s >> 5) * 32 + (d0 >> 4)) * 512 +
                    (((d0 >> 3) & 1) * 32 + (s & 31)) * 8 + (d0 & 7)) = pk;
      }
    }
  } else {
    // C rows=s, cols=d. VF per b: G-layout rows=d (TK=128), K=t.
    fgemm_lds<8>(Xc, x * 8, 16, Wc + 2 * 524288, y * 8, 16, 16, lds, acc);
    const int sbase = x * 128 + (w & 1) * 64;
    const int dbase = y * 128 + (w >> 1) * 64;
#pragma unroll
    for (int i = 0; i < 4; ++i) {
      const int s0 = sbase + i * 16 + (lane >> 4) * 4;
      const int bt = s0 >> 11, t0 = s0 & 2047;
#pragma unroll
      for (int j = 0; j < 4; ++j) {
        const int d = dbase + j * 16 + (lane & 15);
        const float bn = bv[d];
        ushort4 pk;
        pk.x = f2b(acc[i][j][0] + bn);
        pk.y = f2b(acc[i][j][1] + bn);
        pk.z = f2b(acc[i][j][2] + bn);
        pk.w = f2b(acc[i][j][3] + bn);
        *(ushort4*)(VF + (size_t)bt * DIM * SEQ +
                    (size_t)((d >> 5) * 128 + (t0 >> 4)) * 512 +
                    (((t0 >> 3) & 1) * 32 + (d & 31)) * 8 + (t0 & 7)) = pk;
      }
    }
  }
}

// ---- K2: S^T = K Q^T (32x32 mainloop); exp epilogue -> ScF(G) + rowsum ----
__global__ __launch_bounds__(256) void scores_kernel(
    const unsigned short* __restrict__ QF, const unsigned short* __restrict__ KF,
    unsigned short* __restrict__ ScF, float* __restrict__ rowsum)
{
  __shared__ char lds[32768];   // 2 x 16 KB (KC=2)
  const int b = blockIdx.z, x = blockIdx.x, y = blockIdx.y;
  const int lane = threadIdx.x & 63, w = threadIdx.x >> 6;
  const int wm = w & 1, wn = w >> 1;
  floatx16 acc[2][2] = {};
  // A = KF (rows t, TK=32), B = QF (rows s, TK=32); tile 128t x 128s
  fgemm32<2>((const char*)KF + (size_t)b * 2097152, y * 4, 32,
             (const char*)QF + (size_t)b * 2097152, x * 4, 32, 16, lds, acc);

  unsigned short* S = ScF + (size_t)b * SEQ * SEQ / 1;   // G frag base per b
  const float scale = 0.044194173824159216f;  // 1/sqrt(512)
  const int tb = y * 128 + wm * 64;
  const int sb = x * 128 + wn * 64;
  float csum[2] = {0.f, 0.f};
#pragma unroll
  for (int i = 0; i < 2; ++i) {
#pragma unroll
    for (int j = 0; j < 2; ++j) {
      const int s = sb + j * 32 + (lane & 31);
      float e[16];
#pragma unroll
      for (int r = 0; r < 16; ++r) {
        e[r] = __expf(acc[i][j][r] * scale);
        csum[j] += e[r];
      }
#pragma unroll
      for (int q = 0; q < 4; ++q) {
        const int t = tb + i * 32 + (lane >> 5) * 4 + q * 8;
        ushort4 pk;
        pk.x = f2b(e[q * 4 + 0]); pk.y = f2b(e[q * 4 + 1]);
        pk.z = f2b(e[q * 4 + 2]); pk.w = f2b(e[q * 4 + 3]);
        *(ushort4*)(S + (size_t)((s >> 5) * 128 + (t >> 4)) * 512 +
                    (((t >> 3) & 1) * 32 + (s & 31)) * 8 + (t & 7)) = pk;
      }
    }
  }
  // rowsum: csum[j] covers this wave's 64 t for s = sb+j*32+(lane&31)
#pragma unroll
  for (int j = 0; j < 2; ++j) {
    csum[j] += __shfl_xor(csum[j], 32, 64);
    if (lane < 32)
      atomicAdd(rowsum + b * SEQ + sb + j * 32 + lane, csum[j]);
  }
}

// ---- K3: out[s][d] = (ScF . VF) / rowsum[s] (32x32 mainloop) --------------
__global__ __launch_bounds__(256) void pv_kernel(
    const unsigned short* __restrict__ ScF, const unsigned short* __restrict__ VF,
    const float* __restrict__ rowsum, float* __restrict__ out)
{
  __shared__ char lds[32768];   // 2 x 16 KB (KC=2)
  const int b = blockIdx.z, x = blockIdx.x, y = blockIdx.y;
  const int lane = threadIdx.x & 63, w = threadIdx.x >> 6;
  const int wm = w & 1, wn = w >> 1;
  floatx16 acc[2][2] = {};
  // A = ScF (rows s, TK=128), B = VF (rows d, TK=128); tile 128s x 128d
  fgemm32<2>((const char*)ScF + (size_t)b * 8388608, x * 4, 128,
             (const char*)VF + (size_t)b * 2097152, y * 4, 128, 64, lds, acc);

#pragma unroll
  for (int i = 0; i < 2; ++i) {
#pragma unroll
    for (int j = 0; j < 2; ++j) {
      const int d = y * 128 + wn * 64 + j * 32 + (lane & 31);
#pragma unroll
      for (int q = 0; q < 4; ++q) {
        const int s0 = x * 128 + wm * 64 + i * 32 + (lane >> 5) * 4 + q * 8;
        const float4 rs = *(const float4*)(rowsum + b * SEQ + s0);
        float* o = out + ((size_t)b * SEQ + s0) * DIM + d;
        o[0 * DIM] = acc[i][j][q * 4 + 0] * (1.f / rs.x);
        o[1 * DIM] = acc[i][j][q * 4 + 1] * (1.f / rs.y);
        o[2 * DIM] = acc[i][j][q * 4 + 2] * (1.f / rs.z);
        o[3 * DIM] = acc[i][j][q * 4 + 3] * (1.f / rs.w);
      }
    }
  }
}

extern "C" void kernel_launch(void* const* d_in, const int* in_sizes, int n_in,
                              void* d_out, int out_size, void* d_ws, size_t ws_size,
                              hipStream_t stream) {
  const float* X  = (const float*)d_in[0];
  const float* Wq = (const float*)d_in[1];
  const float* bq = (const float*)d_in[2];
  const float* Wk = (const float*)d_in[3];
  const float* bk = (const float*)d_in[4];
  const float* Wv = (const float*)d_in[5];
  const float* bv = (const float*)d_in[6];
  float* out = (float*)d_out;
  char* ws = (char*)d_ws;

  // workspace layout (bytes)
  short8* XbF = (short8*)(ws + 0);                    //  8 MB   (F: rows=b*S+s, K=512)
  short8* WF  = (short8*)(ws + 8388608);              //  1.5 MB (F: rows=n, K=512, x3)
  char*   QF  = ws + 9961472;                         //  8 MB   (G: rows=s, K=d)
  char*   KF  = ws + 18350080;                        //  8 MB   (G: rows=s, K=d)
  char*   VF  = ws + 26738688;                        //  8 MB   (G: rows=d, K=t, per b)
  char*   ScF = ws + 35127296;                        // 32 MB   (G: rows=s, K=t, per b)
  float*  rowsum = (float*)(ws + 68681728);           // 32 KB

  setup_kernel<<<dim3(2048), 256, 0, stream>>>(X, Wq, Wk, Wv, XbF, WF, rowsum);
  qkv_kernel<<<dim3(64, 4, 3), 256, 0, stream>>>(
      XbF, WF, bq, bk, bv,
      (unsigned short*)QF, (unsigned short*)KF, (unsigned short*)VF);
  scores_kernel<<<dim3(16, 16, 4), 256, 0, stream>>>(
      (const unsigned short*)QF, (const unsigned short*)KF,
      (unsigned short*)ScF, rowsum);
  pv_kernel<<<dim3(16, 4, 4), 256, 0, stream>>>(
      (const unsigned short*)ScF, (const unsigned short*)VF, rowsum, out);
}